// Round 4
// baseline (20.163 us; speedup 1.0000x reference)
//
#include <hip/hip_runtime.h>

// ---------------- types / helpers ----------------
typedef short bf16x8 __attribute__((ext_vector_type(8)));
typedef float f32x4 __attribute__((ext_vector_type(4)));

#define NEGV -1000000000.0f

__device__ __forceinline__ unsigned short f2bf(float f) {
    unsigned int u = __float_as_uint(f);
    u += 0x7FFFu + ((u >> 16) & 1u);   // round-to-nearest-even
    return (unsigned short)(u >> 16);
}
__device__ __forceinline__ unsigned int pack2(float a, float b) {
    return (unsigned int)f2bf(a) | ((unsigned int)f2bf(b) << 16);
}

// ---------------- single fused kernel ----------------
// One block per batch b (512 blocks, 256 threads = 4 waves).
// Phase 0: prefetch W2/b1/b2/move_mask/W1-chunk; 129-ary dual binary search for
//          [segs, sege) in sorted batch (3 dependent rounds, all 256 threads).
// Phase 1: ballot-scan cube_mask over the segment, first 64 cubes -> lds_node.
// Phase 2: layer1 [64x256]x[256x128] mfma bf16 (chunk order gf,gf,nf,nf to hide
//          the nf gather), in-flight f32->bf16 W1 transpose into ldsB;
//          layer2 [64x128]x[128x32pad]; masked write.
__global__ void __launch_bounds__(256, 3)
fused_kernel(const float* __restrict__ nf, const float* __restrict__ gf,
             const float* __restrict__ W1, const float* __restrict__ b1,
             const float* __restrict__ W2, const float* __restrict__ b2,
             const int* __restrict__ cube_mask, const int* __restrict__ batch,
             const int* __restrict__ move_mask, float* __restrict__ out, int N) {
    __shared__ __align__(16) char smemAB[(64 * 72 + 128 * 72) * 2];   // ldsA | ldsB, aliased by ldsH
    __shared__ __align__(16) unsigned short ldsW2[32][136];
    __shared__ int lds_node[64];
    __shared__ int wt[4];
    __shared__ unsigned long long swt[4];
    __shared__ int seg[2];
    unsigned short (*ldsA)[72]  = (unsigned short (*)[72])smemAB;
    unsigned short (*ldsB)[72]  = (unsigned short (*)[72])(smemAB + 64 * 72 * 2);
    unsigned short (*ldsH)[136] = (unsigned short (*)[136])smemAB;

    int t = threadIdx.x;
    int blk = blockIdx.x;            // batch index
    int lane = t & 63, w = t >> 6;   // wave id 0..3

    if (t < 64) lds_node[t] = -1;

    // ---- phase 0a: independent prefetches (issue before the search chain) ----
    int w2col = t >> 3, w2k0 = (t & 7) * 16;     // W2T gather: 16 strided f32
    float w2v[16];
#pragma unroll
    for (int j = 0; j < 16; ++j)
        w2v[j] = (w2col < 24) ? W2[(size_t)(w2k0 + j) * 24 + w2col] : 0.f;

    int wm = w >> 1, wn = w & 1;     // wave tile: rows [wm*32,+32), cols [wn*64,+64)
    float b1v[4];
#pragma unroll
    for (int nt = 0; nt < 4; ++nt) b1v[nt] = b1[wn * 64 + nt * 16 + (lane & 15)];
    float b2v[2];
    int mmv[8];
#pragma unroll
    for (int ct = 0; ct < 2; ++ct) {
        int m = ct * 16 + (lane & 15);
        if (m < 24) {
            b2v[ct] = b2[m];
#pragma unroll
            for (int rr = 0; rr < 4; ++rr) {
                int row = w * 16 + (lane >> 4) * 4 + rr;
                mmv[ct * 4 + rr] = move_mask[(size_t)(blk * 64 + row) * 24 + m];
            }
        } else {
            b2v[ct] = 0.f;
#pragma unroll
            for (int rr = 0; rr < 4; ++rr) mmv[ct * 4 + rr] = 0;
        }
    }

    // W1 chunk-2 prefetch (rows 128..191): thread (kp, hblk) reads rows k,k+1 x 16 h
    int kp = t >> 3, hblk = t & 7;
    float4 fW[8];
    {
        const float* s0 = W1 + (size_t)(128 + kp * 2) * 128 + hblk * 16;
#pragma unroll
        for (int i = 0; i < 4; ++i) {
            fW[i]     = *(const float4*)(s0 + i * 4);
            fW[4 + i] = *(const float4*)(s0 + 128 + i * 4);
        }
    }

    // ---- phase 0b: 129-ary dual binary search (targets blk, blk+1) ----
    int half = t >> 7, l = t & 127;
    int target = blk + half;
    int lo = -1, hi = N;
#pragma unroll
    for (int round = 0; round < 3; ++round) {
        int span = hi - lo;
        int pos = lo + (int)(((long long)span * (l + 1)) / 129);
        int v = (pos >= 0) ? batch[pos] : -1;
        unsigned long long bal = __ballot(v >= target);
        if (lane == 0) swt[w] = bal;
        __syncthreads();
        unsigned long long mlow = swt[half * 2], mhigh = swt[half * 2 + 1];
        int j0 = mlow ? __builtin_ctzll(mlow) : (mhigh ? 64 + __builtin_ctzll(mhigh) : -1);
        if (j0 < 0) {
            lo = lo + (int)(((long long)span * 128) / 129);
        } else {
            hi = lo + (int)(((long long)span * (j0 + 1)) / 129);
            if (j0 > 0) lo = lo + (int)(((long long)span * j0) / 129);
        }
        __syncthreads();
    }
    if (l == 0) seg[half] = hi;      // lower_bound(batch, target)

    // ---- stage ldsW2 + ldsB(chunk 2) from regs; refill fW with chunk 3 ----
#pragma unroll
    for (int j = 0; j < 8; ++j)
        *(unsigned int*)&ldsW2[w2col][w2k0 + 2 * j] = pack2(w2v[2 * j], w2v[2 * j + 1]);
#pragma unroll
    for (int j = 0; j < 16; ++j) {
        float a  = ((const float*)&fW[j >> 2])[j & 3];
        float bq = ((const float*)&fW[4 + (j >> 2)])[j & 3];
        *(unsigned int*)&ldsB[hblk * 16 + j][kp * 2] = pack2(a, bq);
    }
    {   // fW <- W1 chunk 3 (rows 192..255)
        const float* s0 = W1 + (size_t)(192 + kp * 2) * 128 + hblk * 16;
#pragma unroll
        for (int i = 0; i < 4; ++i) {
            fW[i]     = *(const float4*)(s0 + i * 4);
            fW[4 + i] = *(const float4*)(s0 + 128 + i * 4);
        }
    }
    // gf chunk-2 (dims 0..63) into fG
    int r = t >> 2, q = t & 3;       // staging row 0..63, quarter (16 floats)
    float4 fG[4];
    {
        const float* srcG = gf + (size_t)blk * 128 + q * 16;
#pragma unroll
        for (int i = 0; i < 4; ++i) fG[i] = *(const float4*)(srcG + i * 4);
    }
    __syncthreads();                 // seg + lds_node init + ldsW2/ldsB visible
    int segs = seg[0], sege = seg[1];

    // ---- phase 1: find first 64 cubes in [segs, sege) ----
    int found = 0;
    for (int pos = segs; pos < sege && found < 64; pos += 256) {
        int i = pos + t;
        int m = (i < sege) ? cube_mask[i] : 0;
        unsigned long long bal = __ballot(m != 0);
        int below = __popcll(bal & ((1ULL << lane) - 1ULL));
        if (lane == 0) wt[w] = __popcll(bal);
        __syncthreads();
        int waveOfs = 0, total = 0;
#pragma unroll
        for (int j = 0; j < 4; ++j) { int c = wt[j]; if (j < w) waveOfs += c; total += c; }
        int rank = found + waveOfs + below;
        if (m && rank < 64) lds_node[rank] = i;
        found += total;
        __syncthreads();
    }

    // ---- phase 2: MLP. Chunk order 2,3,0,1 (gf,gf,nf,nf) ----
    int n = lds_node[r];
    int nrow = (n >= 0) ? n : 0;     // invalid rows read row 0; outputs masked at write
    const float* srcN = nf + (size_t)nrow * 128 + q * 16;
    float4 fN[8];
#pragma unroll
    for (int i = 0; i < 4; ++i) {    // whole nf row share: one gather latency
        fN[i]     = *(const float4*)(srcN + i * 4);
        fN[4 + i] = *(const float4*)(srcN + 64 + i * 4);
    }

    f32x4 acc[2][4];
#pragma unroll
    for (int i = 0; i < 2; ++i)
#pragma unroll
        for (int j = 0; j < 4; ++j) acc[i][j] = (f32x4){0.f, 0.f, 0.f, 0.f};

#define STAGE_A(s0, s1, s2, s3) do {                                             \
        unsigned short tmp[16];                                                  \
        tmp[0]  = f2bf((s0).x); tmp[1]  = f2bf((s0).y); tmp[2]  = f2bf((s0).z); tmp[3]  = f2bf((s0).w); \
        tmp[4]  = f2bf((s1).x); tmp[5]  = f2bf((s1).y); tmp[6]  = f2bf((s1).z); tmp[7]  = f2bf((s1).w); \
        tmp[8]  = f2bf((s2).x); tmp[9]  = f2bf((s2).y); tmp[10] = f2bf((s2).z); tmp[11] = f2bf((s2).w); \
        tmp[12] = f2bf((s3).x); tmp[13] = f2bf((s3).y); tmp[14] = f2bf((s3).z); tmp[15] = f2bf((s3).w); \
        *(bf16x8*)&ldsA[r][q * 16]     = *(bf16x8*)&tmp[0];                      \
        *(bf16x8*)&ldsA[r][q * 16 + 8] = *(bf16x8*)&tmp[8];                      \
    } while (0)

#define STAGE_B() do {                                                           \
        _Pragma("unroll")                                                        \
        for (int j = 0; j < 16; ++j) {                                           \
            float a_  = ((const float*)&fW[j >> 2])[j & 3];                      \
            float b_  = ((const float*)&fW[4 + (j >> 2)])[j & 3];                \
            *(unsigned int*)&ldsB[hblk * 16 + j][kp * 2] = pack2(a_, b_);        \
        }                                                                        \
    } while (0)

#define LOAD_W1(ch) do {                                                         \
        const float* s0_ = W1 + (size_t)((ch) * 64 + kp * 2) * 128 + hblk * 16;  \
        _Pragma("unroll")                                                        \
        for (int i = 0; i < 4; ++i) {                                            \
            fW[i]     = *(const float4*)(s0_ + i * 4);                           \
            fW[4 + i] = *(const float4*)(s0_ + 128 + i * 4);                     \
        }                                                                        \
    } while (0)

#define MFMA_CHUNK() do {                                                        \
        _Pragma("unroll")                                                        \
        for (int ks = 0; ks < 2; ++ks) {                                         \
            int ko = ks * 32 + (lane >> 4) * 8;                                  \
            bf16x8 af[2], bfr[4];                                                \
            _Pragma("unroll")                                                    \
            for (int mt = 0; mt < 2; ++mt)                                       \
                af[mt] = *(const bf16x8*)&ldsA[wm * 32 + mt * 16 + (lane & 15)][ko]; \
            _Pragma("unroll")                                                    \
            for (int nt = 0; nt < 4; ++nt)                                       \
                bfr[nt] = *(const bf16x8*)&ldsB[wn * 64 + nt * 16 + (lane & 15)][ko]; \
            _Pragma("unroll")                                                    \
            for (int mt = 0; mt < 2; ++mt)                                       \
                _Pragma("unroll")                                                \
                for (int nt = 0; nt < 4; ++nt)                                   \
                    acc[mt][nt] = __builtin_amdgcn_mfma_f32_16x16x32_bf16(       \
                        af[mt], bfr[nt], acc[mt][nt], 0, 0, 0);                  \
        }                                                                        \
    } while (0)

    // ci=0: chunk 2 (gf lo). ldsB chunk2 pre-staged.
    STAGE_A(fG[0], fG[1], fG[2], fG[3]);
    __syncthreads();
    {   // refill fG <- gf chunk 3 (dims 64..127)
        const float* srcG = gf + (size_t)blk * 128 + 64 + q * 16;
#pragma unroll
        for (int i = 0; i < 4; ++i) fG[i] = *(const float4*)(srcG + i * 4);
    }
    MFMA_CHUNK();
    __syncthreads();

    // ci=1: chunk 3 (gf hi); fW holds W1 chunk 3
    STAGE_B();
    LOAD_W1(0);
    STAGE_A(fG[0], fG[1], fG[2], fG[3]);
    __syncthreads();
    MFMA_CHUNK();
    __syncthreads();

    // ci=2: chunk 0 (nf lo)
    STAGE_B();
    LOAD_W1(1);
    STAGE_A(fN[0], fN[1], fN[2], fN[3]);
    __syncthreads();
    MFMA_CHUNK();
    __syncthreads();

    // ci=3: chunk 1 (nf hi)
    STAGE_B();
    STAGE_A(fN[4], fN[5], fN[6], fN[7]);
    __syncthreads();
    MFMA_CHUNK();
    __syncthreads();

#undef STAGE_A
#undef STAGE_B
#undef LOAD_W1
#undef MFMA_CHUNK

    // layer1 epilogue: bias + relu -> ldsH (aliases ldsA/ldsB, dead now)
#pragma unroll
    for (int nt = 0; nt < 4; ++nt) {
        int col = wn * 64 + nt * 16 + (lane & 15);
        float bias = b1v[nt];
#pragma unroll
        for (int mt = 0; mt < 2; ++mt) {
            int row0 = wm * 32 + mt * 16 + (lane >> 4) * 4;
#pragma unroll
            for (int rr = 0; rr < 4; ++rr) {
                float v = acc[mt][nt][rr] + bias;
                v = v > 0.f ? v : 0.f;
                ldsH[row0 + rr][col] = f2bf(v);
            }
        }
    }
    __syncthreads();

    // layer2: wave w rows [w*16,+16); K=128 in 4 steps; cols 0..31 (pad of 24)
    f32x4 acc2[2];
    acc2[0] = (f32x4){0.f, 0.f, 0.f, 0.f};
    acc2[1] = (f32x4){0.f, 0.f, 0.f, 0.f};
#pragma unroll
    for (int ks = 0; ks < 4; ++ks) {
        int ko = ks * 32 + (lane >> 4) * 8;
        bf16x8 a2 = *(const bf16x8*)&ldsH[w * 16 + (lane & 15)][ko];
#pragma unroll
        for (int ct = 0; ct < 2; ++ct) {
            bf16x8 bw = *(const bf16x8*)&ldsW2[ct * 16 + (lane & 15)][ko];
            acc2[ct] = __builtin_amdgcn_mfma_f32_16x16x32_bf16(a2, bw, acc2[ct], 0, 0, 0);
        }
    }

    // write out: every (slot, m<24) element written exactly once per call
#pragma unroll
    for (int ct = 0; ct < 2; ++ct) {
        int m = ct * 16 + (lane & 15);
        if (m >= 24) continue;
#pragma unroll
        for (int rr = 0; rr < 4; ++rr) {
            int row = w * 16 + (lane >> 4) * 4 + rr;
            size_t oidx = (size_t)(blk * 64 + row) * 24 + m;
            float v = acc2[ct][rr] + b2v[ct];
            bool keep = (lds_node[row] >= 0) && (mmv[ct * 4 + rr] != 0);
            out[oidx] = keep ? v : NEGV;
        }
    }
}

// ---------------- launcher ----------------
extern "C" void kernel_launch(void* const* d_in, const int* in_sizes, int n_in,
                              void* d_out, int out_size, void* d_ws, size_t ws_size,
                              hipStream_t stream) {
    const float* nf = (const float*)d_in[0];
    const float* gf = (const float*)d_in[1];
    const float* W1 = (const float*)d_in[2];
    const float* b1 = (const float*)d_in[3];
    const float* W2 = (const float*)d_in[4];
    const float* b2 = (const float*)d_in[5];
    const int* cube_mask = (const int*)d_in[6];
    const int* batch     = (const int*)d_in[7];
    const int* move_mask = (const int*)d_in[8];
    float* out = (float*)d_out;

    int N = in_sizes[6];            // 500000
    int B = in_sizes[1] / 128;      // 512

    fused_kernel<<<B, 256, 0, stream>>>(nf, gf, W1, b1, W2, b2,
                                        cube_mask, batch, move_mask, out, N);
    (void)n_in; (void)out_size; (void)d_ws; (void)ws_size;
}